// Round 14
// baseline (726.251 us; speedup 1.0000x reference)
//
#include <hip/hip_runtime.h>

// ============================================================================
// CNF log-density, fused persistent kernel — v15: B-read amortization.
//   - Diagnosis: LDS read pipe is the largest consumer (~1700 b128/feval/CU
//     x 12cy = 20.4k cy vs 36k wall). The val+tan-fused A meant one B-read
//     per MFMA with zero B reuse.
//   - NEW: A_val (32 z rows) and A_tan (32 eps rows) are SEPARATE fragments;
//     one B-read now feeds 2 MFMAs (accV, accT — independent chains).
//     B-reads/wave/feval: 160 -> 88. Per-CU LDS ops -17%.
//   - Geometry: 512 thr = 8 waves = 2 groups x 32 rows x 4-way N-split
//     (wave owns 64 cols). acc = accV[2]+accT[2] = 64 regs (unchanged).
//     LDS = 64KB ring + 2 x (tb 64x264 bf16 + 3 k-slabs [32][72] bf16)
//     = 160768B (identical footprint, 1 block/CU, 2 waves/SIMD).
//   - Layer 4: wave = (A-type, col-tile): val waves write dz->slab, tan waves
//     write Jeps->jb [32][68]; div via per-thread partial + LDS row-reduce.
//   - RK state per thread: 8 dims (y[8], k1/k3 one short8 each) — frees
//     ~30 VGPR and halves combine VALU.
//   - Skeleton (phases, stage-after-barrier slots, __syncthreads flavor,
//     z16 seed, cvt_pk diet, bias hoist) = v13 verbatim. v13=720, v14=715.
// ============================================================================

#define DIM   64
#define HID   256
#define BATCH 32768
#define LOG2PI_HALF_SUM 58.8120661251f   // 32 * log(2*pi)

typedef float  floatx4  __attribute__((ext_vector_type(4)));
typedef float  floatx16 __attribute__((ext_vector_type(16)));
typedef short  short8   __attribute__((ext_vector_type(8)));

// ---- workspace: bf16 weights, fragment-linear, contiguous 40 x 8KB chunks --
// chunk c: W1 c0-3 (kt=c), W2 c4-19, W3 c20-35, W4 c36-39 (4kt x 2 tiles).
#define BOFF   327680    // biases fp32: b1[256] b2[256] b3[256] b4[64]
#define CHUNK  8192
#define NCHUNK 40

// ---- LDS ----
#define TBS         264              // shorts per tb row (256 + 8 pad)
#define TB_BYTES    33792            // 64 rows * 264 * 2
#define SLAB_STR    72               // shorts per slab row (64 + 8 pad)
#define SLAB_SH     2304             // shorts per slab (32*72)
#define RING_BYTES  65536            // 8 x 8KB chunk ring
#define GROUP_BYTES (TB_BYTES + 3 * 4608)            // 47616
#define SMEM_BYTES  (RING_BYTES + 2 * GROUP_BYTES)   // 160768 -> 1 block/CU
#define JBS 68                       // jb floats per row (64 + 4 pad, 16B-aligned)

#define MFMA32(a, b, c) __builtin_amdgcn_mfma_f32_32x32x16_bf16(a, b, c, 0, 0, 0)

__device__ __forceinline__ unsigned cvtpk(float lo, float hi) {
    unsigned r;
    asm("v_cvt_pk_bf16_f32 %0, %1, %2" : "=v"(r) : "v"(lo), "v"(hi));
    return r;
}

__device__ __forceinline__ float bf2f(short s) {
    union { float f; unsigned u; } v;
    v.u = ((unsigned)(unsigned short)s) << 16;
    return v.f;
}

__device__ __forceinline__ float fast_tanh(float x) {
    float e = __expf(2.0f * x);
    return 1.0f - 2.0f * __builtin_amdgcn_rcpf(e + 1.0f);
}

// ---- async global->LDS: 16B/lane, LDS dest = wave-uniform base + lane*16 ----
__device__ __forceinline__ void gld_lds16(const char* g, char* l) {
    __builtin_amdgcn_global_load_lds(
        (const __attribute__((address_space(1))) void*)g,
        (__attribute__((address_space(3))) void*)l, 16, 0, 0);
}

// Stage ws chunk g into ring slot g%8: each of 8 waves DMAs its 1KB slice.
__device__ __forceinline__ void stage_dma(const char* __restrict__ ws, char* ring,
                                          int g, int wave, int lane) {
    const char* src = ws + g * CHUNK + wave * 1024 + lane * 16;
    char* dst = ring + (g & 7) * CHUNK + wave * 1024;
    gld_lds16(src, dst);
}

// accV/accT (2 ntl x 32 rows x 32 cols) -> tb: h rows 0-31, t rows 32-63.
__device__ __forceinline__ void transpose_acts(const floatx16 (&aV)[2],
                                               const floatx16 (&aT)[2],
                                               const float (&bv)[2], short* tb,
                                               int sw, int l31, int hi) {
    unsigned short* tbu = (unsigned short*)tb;
#pragma unroll
    for (int ntl = 0; ntl < 2; ntl++) {
        const int col = (sw * 2 + ntl) * 32 + l31;
#pragma unroll
        for (int p = 0; p < 8; p++) {
            const int r0 = 2 * p, r1 = r0 + 1;
            const int rv0 = (r0 & 3) + 8 * (r0 >> 2) + 4 * hi;
            const int rv1 = rv0 + 1;
            float h0 = fast_tanh(aV[ntl][r0] + bv[ntl]);
            float h1 = fast_tanh(aV[ntl][r1] + bv[ntl]);
            float t0 = __builtin_fmaf(-h0, h0, 1.0f) * aT[ntl][r0];
            float t1 = __builtin_fmaf(-h1, h1, 1.0f) * aT[ntl][r1];
            unsigned hp = cvtpk(h0, h1);
            unsigned tp = cvtpk(t0, t1);
            tbu[rv0 * TBS + col]        = (unsigned short)hp;
            tbu[rv1 * TBS + col]        = (unsigned short)(hp >> 16);
            tbu[(32 + rv0) * TBS + col] = (unsigned short)tp;
            tbu[(32 + rv1) * TBS + col] = (unsigned short)(tp >> 16);
        }
    }
}

// ---- one ODE f-eval: dz bf16 -> slab[sout]; returns div (thread's row) ----
__device__ __forceinline__ float feval(const float (&zs)[8], short8 e8,
                                       const char* __restrict__ ws, char* ring,
                                       short* tb, short* slabs, int sout,
                                       const floatx16& z16,
                                       const float (&b1r)[2], const float (&b2r)[2],
                                       const float (&b3r)[2], float b4v,
                                       int lane, int rr, int dd0, int sw,
                                       int l31, int hi, int wave) {
    // layer-1 A: every thread writes its 8 zs dims (row rr) + 8 eps dims.
    {
        uint4 zp = { cvtpk(zs[0], zs[1]), cvtpk(zs[2], zs[3]),
                     cvtpk(zs[4], zs[5]), cvtpk(zs[6], zs[7]) };
        *(uint4*)&tb[rr * TBS + dd0]         = zp;
        *(short8*)&tb[(32 + rr) * TBS + dd0] = e8;
    }

    floatx16 accV[2], accT[2];

    // ---------- layer 1 (one phase): read chunks 0-3, stage 4-7 ----------
    __syncthreads();                       // input + chunk 0-3 DMAs visible
#pragma unroll
    for (int s = 0; s < 4; s++) stage_dma(ws, ring, 4 + s, wave, lane);
#pragma unroll
    for (int G = 0; G < 4; G++) {
        short8 aV = *(const short8*)&tb[l31 * TBS + G * 16 + hi * 8];
        short8 aT = *(const short8*)&tb[(32 + l31) * TBS + G * 16 + hi * 8];
        const char* bp = ring + (G & 7) * CHUNK;
        __builtin_amdgcn_s_setprio(1);
#pragma unroll
        for (int ntl = 0; ntl < 2; ntl++) {
            short8 b = *(const short8*)(bp + (sw * 2 + ntl) * 1024 + lane * 16);
            accV[ntl] = MFMA32(aV, b, (G == 0) ? z16 : accV[ntl]);
            accT[ntl] = MFMA32(aT, b, (G == 0) ? z16 : accT[ntl]);
        }
        __builtin_amdgcn_s_setprio(0);
    }
    __syncthreads();                       // tb reads done before overwrite
    transpose_acts(accV, accT, b1r, tb, sw, l31, hi);

    // ---------- layers 2,3: 4 phases each (chunks 4-19 / 20-35) ----------
#pragma unroll 1
    for (int layer = 0; layer < 2; layer++) {
        const int gb = 4 + layer * 16;
#pragma unroll
        for (int pp = 0; pp < 4; pp++) {
            const int c0 = gb + pp * 4;
            __syncthreads();
#pragma unroll
            for (int s = 0; s < 4; s++) stage_dma(ws, ring, c0 + 4 + s, wave, lane);
#pragma unroll
            for (int cc = 0; cc < 4; cc++) {
                const int kt = pp * 4 + cc;
                short8 aV = *(const short8*)&tb[l31 * TBS + kt * 16 + hi * 8];
                short8 aT = *(const short8*)&tb[(32 + l31) * TBS + kt * 16 + hi * 8];
                const char* bp = ring + ((c0 + cc) & 7) * CHUNK;
                __builtin_amdgcn_s_setprio(1);
#pragma unroll
                for (int ntl = 0; ntl < 2; ntl++) {
                    short8 b = *(const short8*)(bp + (sw * 2 + ntl) * 1024 + lane * 16);
                    accV[ntl] = MFMA32(aV, b, (pp == 0 && cc == 0) ? z16 : accV[ntl]);
                    accT[ntl] = MFMA32(aT, b, (pp == 0 && cc == 0) ? z16 : accT[ntl]);
                }
                __builtin_amdgcn_s_setprio(0);
            }
        }
        __syncthreads();                   // tb reads done before overwrite
        transpose_acts(accV, accT, layer ? b3r : b2r, tb, sw, l31, hi);
    }

    // ---------- layer 4 (one phase): wave = (A-type, col-tile) ----------
    const int atan = sw >> 1, tile = sw & 1;
    floatx16 a4;
    __syncthreads();                       // transpose + chunks 36-39 visible
#pragma unroll
    for (int s = 0; s < 4; s++) stage_dma(ws, ring, s, wave, lane);
#pragma unroll
    for (int c = 0; c < 4; c++) {
        const char* bp = ring + ((36 + c) & 7) * CHUNK;
        __builtin_amdgcn_s_setprio(1);
#pragma unroll
        for (int k4 = 0; k4 < 4; k4++) {
            const int kt = c * 4 + k4;
            short8 a = *(const short8*)&tb[(atan * 32 + l31) * TBS + kt * 16 + hi * 8];
            short8 b = *(const short8*)(bp + (k4 * 2 + tile) * 1024 + lane * 16);
            a4 = (c == 0 && k4 == 0) ? MFMA32(a, b, z16) : MFMA32(a, b, a4);
        }
        __builtin_amdgcn_s_setprio(0);
    }
    __syncthreads();                       // tb A-reads done; overlay jb

    // ---- epilogue: tan waves -> Jeps in jb [32][68]; val waves -> dz slab ----
    float* jb  = (float*)tb;
    float* scr = (float*)tb + 32 * JBS;    // [32][8] div partials
    if (atan) {
#pragma unroll
        for (int p = 0; p < 8; p++) {
            const int r0 = 2 * p, r1 = r0 + 1;
            const int rv0 = (r0 & 3) + 8 * (r0 >> 2) + 4 * hi;
            jb[rv0 * JBS + tile * 32 + l31]       = a4[r0];
            jb[(rv0 + 1) * JBS + tile * 32 + l31] = a4[r1];
        }
    } else {
        unsigned short* slu = (unsigned short*)(slabs + sout * SLAB_SH);
#pragma unroll
        for (int p = 0; p < 8; p++) {
            const int r0 = 2 * p, r1 = r0 + 1;
            const int rv0 = (r0 & 3) + 8 * (r0 >> 2) + 4 * hi;
            unsigned dp = cvtpk(a4[r0] + b4v, a4[r1] + b4v);
            slu[rv0 * SLAB_STR + tile * 32 + l31]       = (unsigned short)dp;
            slu[(rv0 + 1) * SLAB_STR + tile * 32 + l31] = (unsigned short)(dp >> 16);
        }
    }
    __syncthreads();                       // jb + slab visible
    // div: per-thread partial over its 8 dims, then LDS row-reduce.
    const int oct = (sw >> 1) * 4 + (lane >> 4);
    {
        floatx4 j0 = *(const floatx4*)&jb[rr * JBS + dd0];
        floatx4 j1 = *(const floatx4*)&jb[rr * JBS + dd0 + 4];
        float psum = 0.f;
#pragma unroll
        for (int j = 0; j < 4; j++)
            psum += j0[j] * bf2f(e8[j]) + j1[j] * bf2f(e8[4 + j]);
        scr[rr * 8 + oct] = psum;
    }
    __syncthreads();
    float div;
    {
        floatx4 s0 = *(const floatx4*)&scr[rr * 8];
        floatx4 s1 = *(const floatx4*)&scr[rr * 8 + 4];
        div = s0.x + s0.y + s0.z + s0.w + s1.x + s1.y + s1.z + s1.w;
    }
    __syncthreads();                       // jb/scr dead before next feval tb
    return div;
}

#define SL8(s) (*(const short8*)&slabs[(s) * SLAB_SH + rr * SLAB_STR + dd0])

__global__ void __launch_bounds__(512, 2)
cnf_main(const float* __restrict__ x, const float* __restrict__ eps,
         const char* __restrict__ ws, float* __restrict__ out) {
    extern __shared__ char smem[];
    const int tid  = threadIdx.x;
    const int lane = tid & 63;
    const int wave = tid >> 6;
    const int group = wave >> 2, sw = wave & 3;
    const int m = lane & 15, kq = lane >> 4;
    const int l31 = lane & 31, hi = lane >> 5;
    const int rr  = (sw & 1) * 16 + m;        // row 0..31 within group
    const int dd0 = (sw >> 1) * 32 + kq * 8;  // dim octet base 0..56
    char*  ring  = smem;
    short* tb    = (short*)(smem + RING_BYTES + group * GROUP_BYTES);
    short* slabs = (short*)(smem + RING_BYTES + group * GROUP_BYTES + TB_BYTES);
    const int row = blockIdx.x * 64 + group * 32 + rr;

    // per-thread state: 8 dims of one row
    float y[8];
    short8 e8;
    {
        floatx4 vx0 = *(const floatx4*)(x   + row * DIM + dd0);
        floatx4 vx1 = *(const floatx4*)(x   + row * DIM + dd0 + 4);
        floatx4 ve0 = *(const floatx4*)(eps + row * DIM + dd0);
        floatx4 ve1 = *(const floatx4*)(eps + row * DIM + dd0 + 4);
#pragma unroll
        for (int j = 0; j < 4; j++) { y[j] = vx0[j]; y[4 + j] = vx1[j]; }
        unsigned p0 = cvtpk(ve0[0], ve0[1]), p1 = cvtpk(ve0[2], ve0[3]);
        unsigned p2 = cvtpk(ve1[0], ve1[1]), p3 = cvtpk(ve1[2], ve1[3]);
        e8[0]=(short)p0; e8[1]=(short)(p0>>16); e8[2]=(short)p1; e8[3]=(short)(p1>>16);
        e8[4]=(short)p2; e8[5]=(short)(p2>>16); e8[6]=(short)p3; e8[7]=(short)(p3>>16);
    }

    // persistent zero accumulator (C seed)
    floatx16 z16;
#pragma unroll
    for (int i = 0; i < 16; i++) z16[i] = 0.0f;

    // bias hoist: wave's cols = (sw*2+ntl)*32 + l31
    const float* bias = (const float*)(ws + BOFF);
    float b1r[2], b2r[2], b3r[2];
#pragma unroll
    for (int ntl = 0; ntl < 2; ntl++) {
        const int col = (sw * 2 + ntl) * 32 + l31;
        b1r[ntl] = bias[col];
        b2r[ntl] = bias[256 + col];
        b3r[ntl] = bias[512 + col];
    }
    const float b4v = bias[768 + (sw & 1) * 32 + l31];

    // zero both groups' slabs (0-coeff combines must not FMA garbage)
    {
        short8 z = {0, 0, 0, 0, 0, 0, 0, 0};
        for (int k = tid; k < 1728; k += 512) {
            int g = k / 864, u = k - g * 864;
            short* sb = (short*)(smem + RING_BYTES + g * GROUP_BYTES + TB_BYTES);
            *(short8*)&sb[u * 8] = z;
        }
    }
    __syncthreads();                       // slab zeros visible to all

    // prologue: stage chunks 0-3 (first feval's phase-1 barrier syncs them)
#pragma unroll
    for (int s = 0; s < 4; s++) stage_dma(ws, ring, s, wave, lane);

    float ylogp = 0.f;
    short8 zero8 = {0, 0, 0, 0, 0, 0, 0, 0};
    short8 k1 = zero8, k3 = zero8;

#pragma unroll 1
    for (int st = 0; st < 24; st++) {
        const int stage = st % 6;
        float c1, c2, c3, c4, c5, bw; int sout;
        switch (stage) {
            case 0: c1=0.f;           c2=0.f;            c3=0.f;           c4=0.f;            c5=0.f;            bw=0.022786458f;  sout=0; break;
            case 1: c1=0.05f;         c2=0.f;            c3=0.f;           c4=0.f;            c5=0.f;            bw=0.f;           sout=0; break;
            case 2: c1=0.01875f;      c2=0.05625f;       c3=0.f;           c4=0.f;            c5=0.f;            bw=0.112309075f;  sout=1; break;
            case 3: c1=0.244444444f;  c2=-0.933333333f;  c3=0.888888889f;  c4=0.f;            c5=0.f;            bw=0.162760417f;  sout=1; break;
            case 4: c1=0.738149672f;  c2=-2.898948331f;  c3=2.455723213f;  c4=-0.072702332f;  c5=0.f;            bw=-0.080593989f; sout=2; break;
            default:c1=0.711568813f;  c2=-2.689393939f;  c3=2.226605679f;  c4=0.069602273f;   c5=-0.068382826f;  bw=0.032738095f;  sout=0; break;
        }

        // zs = y + c1 k1(regs) + c2 slab0 + c3 k3(regs) + c4 slab1 + c5 slab2
        float zs[8];
        {
            short8 k2 = SL8(0), k4 = SL8(1), k5 = SL8(2);
#pragma unroll
            for (int j = 0; j < 8; j++)
                zs[j] = y[j] + c1 * bf2f(k1[j]) + c2 * bf2f(k2[j])
                             + c3 * bf2f(k3[j]) + c4 * bf2f(k4[j])
                             + c5 * bf2f(k5[j]);
        }

        const float d = feval(zs, e8, ws, ring, tb, slabs, sout, z16,
                              b1r, b2r, b3r, b4v,
                              lane, rr, dd0, sw, l31, hi, wave);

        if (stage == 0) k1 = SL8(0);       // k1 -> regs (slot 0 -> k2 next)
        if (stage == 2) k3 = SL8(1);       // k3 -> regs (slot 1 -> k4 next)
        if (stage == 5) {
            // y += b1 k1 + b3 k3 + b4 slab1 + b5 slab2 + b6 slab0
            short8 k4 = SL8(1), k5 = SL8(2), k6 = SL8(0);
#pragma unroll
            for (int j = 0; j < 8; j++)
                y[j] += 0.022786458f * bf2f(k1[j]) + 0.112309075f * bf2f(k3[j])
                      + 0.162760417f * bf2f(k4[j]) - 0.080593989f * bf2f(k5[j])
                      + 0.032738095f * bf2f(k6[j]);
        }
        ylogp -= bw * d;
    }

    // final: nrm = sum over 64 dims of y^2, via LDS row-reduce (tb is free)
    {
        float pn = 0.f;
#pragma unroll
        for (int j = 0; j < 8; j++) pn += y[j] * y[j];
        float* scr2 = (float*)tb;
        const int oct = (sw >> 1) * 4 + kq;
        scr2[rr * 8 + oct] = pn;
    }
    __syncthreads();
    if ((sw >> 1) == 0 && kq == 0) {
        float* scr2 = (float*)tb;
        float nrm = 0.f;
#pragma unroll
        for (int i = 0; i < 8; i++) nrm += scr2[rr * 8 + i];
        float res = -0.5f * nrm - LOG2PI_HALF_SUM - ylogp;
        out[blockIdx.x * 64 + group * 32 + rr] = res;
    }
}

// ---- weight pre-shuffle: fp32 [N][K] -> bf16 fragment-linear (32x32x16) ----
// frag = ktile*NT + ntile; lane l holds W[ntile*32 + (l&31)][ktile*16 + (l>>5)*8 + 0..7]
__global__ void prep_w(const float* __restrict__ W, short* __restrict__ outp,
                       int K, int NT, int KT) {
    int slot  = blockIdx.x * 256 + threadIdx.x;
    int total = KT * NT * 64;
    if (slot >= total) return;
    int lane  = slot & 63, frag = slot >> 6;
    int ntile = frag % NT, ktile = frag / NT;
    int n = ntile * 32 + (lane & 31);
    int k = ktile * 16 + (lane >> 5) * 8;
    short8 v;
#pragma unroll
    for (int j = 0; j < 8; j++) {
        union { float f; unsigned u; } w; w.f = W[n * K + k + j];
        unsigned r = w.u + 0x7FFFu + ((w.u >> 16) & 1u);
        v[j] = (short)(r >> 16);
    }
    *(short8*)(outp + slot * 8) = v;
}

__global__ void prep_b(const float* __restrict__ b1, const float* __restrict__ b2,
                       const float* __restrict__ b3, const float* __restrict__ b4,
                       float* __restrict__ dst) {
    int i = blockIdx.x * 256 + threadIdx.x;
    if (i < 256)      dst[i] = b1[i];
    else if (i < 512) dst[i] = b2[i - 256];
    else if (i < 768) dst[i] = b3[i - 512];
    else if (i < 832) dst[i] = b4[i - 768];
}

extern "C" void kernel_launch(void* const* d_in, const int* in_sizes, int n_in,
                              void* d_out, int out_size, void* d_ws, size_t ws_size,
                              hipStream_t stream) {
    const float* x   = (const float*)d_in[0];
    const float* eps = (const float*)d_in[1];
    const float* W1  = (const float*)d_in[2];
    const float* b1  = (const float*)d_in[3];
    const float* W2  = (const float*)d_in[4];
    const float* b2  = (const float*)d_in[5];
    const float* W3  = (const float*)d_in[6];
    const float* b3  = (const float*)d_in[7];
    const float* W4  = (const float*)d_in[8];
    const float* b4  = (const float*)d_in[9];
    char*  ws  = (char*)d_ws;
    float* out = (float*)d_out;

    static bool attr_set = false;
    if (!attr_set) {
        hipFuncSetAttribute(reinterpret_cast<const void*>(cnf_main),
                            hipFuncAttributeMaxDynamicSharedMemorySize, SMEM_BYTES);
        attr_set = true;
    }

    // W1: KT=4, NT=8  -> 32 frags  @ ws+0       (32KB,  chunks 0-3)
    // W2: KT=16,NT=8  -> 128 frags @ ws+32768   (128KB, chunks 4-19)
    // W3: KT=16,NT=8  -> 128 frags @ ws+163840  (128KB, chunks 20-35)
    // W4: KT=16,NT=2  -> 32 frags  @ ws+294912  (32KB,  chunks 36-39)
    prep_w<<<8,  256, 0, stream>>>(W1, (short*)(ws + 0),      64,  8, 4);
    prep_w<<<32, 256, 0, stream>>>(W2, (short*)(ws + 32768),  256, 8, 16);
    prep_w<<<32, 256, 0, stream>>>(W3, (short*)(ws + 163840), 256, 8, 16);
    prep_w<<<8,  256, 0, stream>>>(W4, (short*)(ws + 294912), 256, 2, 16);
    prep_b<<<4, 256, 0, stream>>>(b1, b2, b3, b4, (float*)(ws + BOFF));

    cnf_main<<<BATCH / 64, 512, SMEM_BYTES, stream>>>(x, eps, ws, out);
}